// Round 1
// baseline (457.980 us; speedup 1.0000x reference)
//
#include <hip/hip_runtime.h>
#include <stdint.h>

// ---------------------------------------------------------------------------
// MultiHeadAttentionWithRelativePosition  (B=8, H=16, L=768, D=1024, dk=64)
// Plan: cast->bf16, 3 proj GEMMs (Q scaled by 1/8, V written transposed),
// barrier-free attention (S-row in LDS, rel bias via sheared MFMA window),
// final GEMM with bias -> fp32 out.
// ---------------------------------------------------------------------------

#define DEVFN static __device__ __forceinline__

typedef __bf16 bf16x8 __attribute__((ext_vector_type(8)));
typedef float f32x4 __attribute__((ext_vector_type(4)));

DEVFN uint16_t f2bf(float f) {
  uint32_t u = __builtin_bit_cast(uint32_t, f);
  u += 0x7fffu + ((u >> 16) & 1u);   // RNE
  return (uint16_t)(u >> 16);
}
DEVFN float bf2f(uint16_t h) {
  uint32_t u = ((uint32_t)h) << 16;
  return __builtin_bit_cast(float, u);
}
DEVFN bf16x8 ldg8(const uint16_t* p) { return *reinterpret_cast<const bf16x8*>(p); }

DEVFN void load_lds16(const void* g, void* l) {
  __builtin_amdgcn_global_load_lds((const __attribute__((address_space(1))) uint32_t*)g,
                                   (__attribute__((address_space(3))) uint32_t*)l,
                                   16, 0, 0);
}

// ---------------- workspace layout (uint16 element offsets) ----------------
// Xq,Xk,Xv: bf16 casts of inputs [6144,1024]; Wq..Wo: bf16 weights [1024,1024]
// Eb: bf16 rel emb [1535,64]; Qh,Kh: [B,H,L,64]; Vt: [B,H,64,L]; Ao: [B,L,1024]
static const size_t OXQ = 0;
static const size_t OXK = 6291456;
static const size_t OXV = 12582912;
static const size_t OWQ = 18874368;
static const size_t OWK = 19922944;
static const size_t OWV = 20971520;
static const size_t OWO = 22020096;
static const size_t OEB = 23068672;
static const size_t OQH = 23166912;
static const size_t OKH = 29458368;
static const size_t OVT = 35749824;
static const size_t OAO = 42041280;

// ------------------------------ cast kernel --------------------------------
__global__ __launch_bounds__(256) void cast_kernel(
    const float* __restrict__ q, const float* __restrict__ k, const float* __restrict__ v,
    const float* __restrict__ wq, const float* __restrict__ wk, const float* __restrict__ wv,
    const float* __restrict__ wo, const float* __restrict__ e, uint16_t* __restrict__ ws)
{
  constexpr int NQ = 6291456 / 4, NW = 1048576 / 4, NE = 98240 / 4;
  constexpr int TOT = 3 * NQ + 4 * NW + NE;
  for (int i = blockIdx.x * blockDim.x + threadIdx.x; i < TOT;
       i += gridDim.x * blockDim.x) {
    const float* src; uint16_t* dst; int off = i;
    if (off < NQ)              { src = q;  dst = ws + OXQ; }
    else if ((off -= NQ) < NQ) { src = k;  dst = ws + OXK; }
    else if ((off -= NQ) < NQ) { src = v;  dst = ws + OXV; }
    else if ((off -= NQ) < NW) { src = wq; dst = ws + OWQ; }
    else if ((off -= NW) < NW) { src = wk; dst = ws + OWK; }
    else if ((off -= NW) < NW) { src = wv; dst = ws + OWV; }
    else if ((off -= NW) < NW) { src = wo; dst = ws + OWO; }
    else { off -= NW;            src = e;  dst = ws + OEB; }
    float4 f = reinterpret_cast<const float4*>(src)[off];
    ushort4 u;
    u.x = f2bf(f.x); u.y = f2bf(f.y); u.z = f2bf(f.z); u.w = f2bf(f.w);
    reinterpret_cast<ushort4*>(dst)[off] = u;
  }
}

// ------------------------------ GEMM (C = A @ Bw^T) ------------------------
// MODE 0: Q proj  -> Qh bf16 [B,H,L,64], (v+bias)*0.125
// MODE 1: K proj  -> Kh bf16 [B,H,L,64], v+bias
// MODE 2: V^T     -> A=Wv, Bw=Xv, C[hd][bl] -> Vt bf16 [B,H,64,L], bias by row
// MODE 3: O proj  -> fp32 d_out [6144,1024], v+bias
template<int MODE, int M, int N>
__global__ __launch_bounds__(256, 2) void gemm_bt(
    const uint16_t* __restrict__ A, const uint16_t* __restrict__ Bw,
    const float* __restrict__ bias, void* __restrict__ outp)
{
  constexpr int K = 1024;
  __shared__ uint16_t As[128 * 32];
  __shared__ uint16_t Bs[128 * 32];
  const int tid = threadIdx.x, wave = tid >> 6, lane = tid & 63;
  const int quad = lane >> 4, lc = lane & 15;
  const int m0 = blockIdx.y * 128, n0 = blockIdx.x * 128;
  const int wm = (wave >> 1) * 64, wn = (wave & 1) * 64;
  const int srow = lane >> 2, schunk = (lane & 3) * 8;

  f32x4 acc[4][4];
#pragma unroll
  for (int i = 0; i < 4; ++i)
#pragma unroll
    for (int j = 0; j < 4; ++j) acc[i][j] = (f32x4){0.f, 0.f, 0.f, 0.f};

  for (int k0 = 0; k0 < K; k0 += 32) {
    __syncthreads();
#pragma unroll
    for (int j = 0; j < 2; ++j) {
      int r = (wave * 2 + j) * 16 + srow;
      load_lds16(A + (size_t)(m0 + r) * K + k0 + schunk, &As[((wave * 2 + j) * 16) * 32]);
      load_lds16(Bw + (size_t)(n0 + r) * K + k0 + schunk, &Bs[((wave * 2 + j) * 16) * 32]);
    }
    __syncthreads();
    bf16x8 af[4], bfr[4];
#pragma unroll
    for (int t = 0; t < 4; ++t) {
      af[t]  = *reinterpret_cast<const bf16x8*>(&As[(wm + t * 16 + lc) * 32 + quad * 8]);
      bfr[t] = *reinterpret_cast<const bf16x8*>(&Bs[(wn + t * 16 + lc) * 32 + quad * 8]);
    }
#pragma unroll
    for (int i = 0; i < 4; ++i)
#pragma unroll
      for (int j = 0; j < 4; ++j)
        acc[i][j] = __builtin_amdgcn_mfma_f32_16x16x32_bf16(af[i], bfr[j], acc[i][j], 0, 0, 0);
  }

  // epilogue. Blocks never straddle a batch (768 % 128 has 6 tiles per batch).
  const int bM = (m0 + wm) / 768;   // batch from rows (modes 0,1,3; unused mode 2)
  const int bN = n0 / 768;          // batch from cols (mode 2)
#pragma unroll
  for (int i = 0; i < 4; ++i)
#pragma unroll
    for (int j = 0; j < 4; ++j)
#pragma unroll
      for (int r = 0; r < 4; ++r) {
        int mg = m0 + wm + i * 16 + quad * 4 + r;
        int ng = n0 + wn + j * 16 + lc;
        float v = acc[i][j][r];
        if (MODE == 0 || MODE == 1) {
          v += bias[ng];
          if (MODE == 0) v *= 0.125f;          // 1/sqrt(64) folded into Q
          int lr = mg - bM * 768;
          int h = ng >> 6, d = ng & 63;
          ((uint16_t*)outp)[(((size_t)(bM * 16 + h) * 768 + lr) << 6) + d] = f2bf(v);
        } else if (MODE == 2) {
          v += bias[mg];                        // bias indexed by hd row
          int lr = ng - bN * 768;
          ((uint16_t*)outp)[(size_t)bN * 786432 + (size_t)mg * 768 + lr] = f2bf(v);
        } else {
          v += bias[ng];
          ((float*)outp)[(size_t)mg * 1024 + ng] = v;
        }
      }
}

// ------------------------------ attention ----------------------------------
// grid (24 qtiles, 128 bh), block 128 = 2 waves; each wave owns 16 q rows.
// S row-block [16][768] bf16 in LDS (pad to 776 for 16B-aligned b128 reads).
__global__ __launch_bounds__(128) void attn_kernel(
    const uint16_t* __restrict__ Qh, const uint16_t* __restrict__ Kh,
    const uint16_t* __restrict__ Vt, const uint16_t* __restrict__ Eb,
    uint16_t* __restrict__ Ao)
{
  constexpr int L = 768, DK = 64, SP = 776;
  __shared__ uint16_t S[2][16][SP];
  __shared__ float linv[2][16];
  const int wave = threadIdx.x >> 6, lane = threadIdx.x & 63;
  const int quad = lane >> 4, lc = lane & 15;
  const int bh = blockIdx.y;
  const int qw = blockIdx.x * 32 + wave * 16;

  // Q fragments (scale already folded in): A[m=lc][k=quad*8+j], kb=0/1
  const uint16_t* Qp = Qh + ((size_t)bh * L + qw) * DK;
  bf16x8 qf0 = ldg8(Qp + lc * DK + quad * 8);
  bf16x8 qf1 = ldg8(Qp + lc * DK + 32 + quad * 8);

  // ---- rel-position phase: P[qi,t]=q.E[tbase+t]; shear k = t + qi - 15 ----
  const int tbase = 752 - qw;              // 767 - qw - 15; always >= 0
  for (int nt = 0; nt < 49; ++nt) {
    int trow = tbase + nt * 16 + lc;
    trow = trow > 1534 ? 1534 : trow;      // only last padded col; discarded
    const uint16_t* ep = Eb + trow * DK + quad * 8;
    bf16x8 e0 = ldg8(ep);
    bf16x8 e1 = ldg8(ep + 32);
    f32x4 a = (f32x4){0.f, 0.f, 0.f, 0.f};
    a = __builtin_amdgcn_mfma_f32_16x16x32_bf16(qf0, e0, a, 0, 0, 0);
    a = __builtin_amdgcn_mfma_f32_16x16x32_bf16(qf1, e1, a, 0, 0, 0);
    const int kb = nt * 16 + lc - 15;
#pragma unroll
    for (int r = 0; r < 4; ++r) {
      int qi = quad * 4 + r;
      int kk = kb + qi;                    // each (qi,k) covered exactly once
      if (kk >= 0 && kk < L) S[wave][qi][kk] = f2bf(a[r]);
    }
  }

  // ---- content phase: S += Q K^T ----
  const uint16_t* Kp = Kh + (size_t)bh * L * DK;
  for (int nt = 0; nt < 48; ++nt) {
    const uint16_t* kp = Kp + (nt * 16 + lc) * DK + quad * 8;
    bf16x8 k0 = ldg8(kp);
    bf16x8 k1 = ldg8(kp + 32);
    f32x4 a = (f32x4){0.f, 0.f, 0.f, 0.f};
    a = __builtin_amdgcn_mfma_f32_16x16x32_bf16(qf0, k0, a, 0, 0, 0);
    a = __builtin_amdgcn_mfma_f32_16x16x32_bf16(qf1, k1, a, 0, 0, 0);
    int col = nt * 16 + lc;
#pragma unroll
    for (int r = 0; r < 4; ++r) {
      int qi = quad * 4 + r;
      float s = bf2f(S[wave][qi][col]) + a[r];
      S[wave][qi][col] = f2bf(s);
    }
  }

  // ---- softmax (two passes; lane -> row lc, strip quad*192) ----
  {
    const int row = lc, c0 = quad * 192;
    const uint4* sp = reinterpret_cast<const uint4*>(&S[wave][row][c0]);
    float mx = -1e30f;
#pragma unroll 4
    for (int j = 0; j < 24; ++j) {
      uint4 u = sp[j];
      uint32_t w[4] = {u.x, u.y, u.z, u.w};
#pragma unroll
      for (int t = 0; t < 4; ++t) {
        mx = fmaxf(mx, fmaxf(bf2f((uint16_t)(w[t] & 0xffff)),
                             bf2f((uint16_t)(w[t] >> 16))));
      }
    }
    mx = fmaxf(mx, __shfl_xor(mx, 16, 64));
    mx = fmaxf(mx, __shfl_xor(mx, 32, 64));
    float sum = 0.f;
    uint4* spw = reinterpret_cast<uint4*>(&S[wave][row][c0]);
#pragma unroll 4
    for (int j = 0; j < 24; ++j) {
      uint4 u = spw[j];
      uint32_t w[4] = {u.x, u.y, u.z, u.w};
      uint32_t o[4];
#pragma unroll
      for (int t = 0; t < 4; ++t) {
        float a = __expf(bf2f((uint16_t)(w[t] & 0xffff)) - mx);
        float b = __expf(bf2f((uint16_t)(w[t] >> 16)) - mx);
        sum += a + b;
        o[t] = (uint32_t)f2bf(a) | ((uint32_t)f2bf(b) << 16);
      }
      uint4 vv; vv.x = o[0]; vv.y = o[1]; vv.z = o[2]; vv.w = o[3];
      spw[j] = vv;
    }
    sum += __shfl_xor(sum, 16, 64);
    sum += __shfl_xor(sum, 32, 64);
    if (quad == 0) linv[wave][row] = 1.0f / sum;
  }

  // ---- PV: O[16,64] += P[16,768] @ V[768,64] (V^T layout: contiguous k) ----
  f32x4 o[4];
#pragma unroll
  for (int t = 0; t < 4; ++t) o[t] = (f32x4){0.f, 0.f, 0.f, 0.f};
  const uint16_t* Vp = Vt + (size_t)bh * DK * L;
  for (int kb = 0; kb < 24; ++kb) {
    bf16x8 af = *reinterpret_cast<const bf16x8*>(&S[wave][lc][kb * 32 + quad * 8]);
#pragma unroll
    for (int nt = 0; nt < 4; ++nt) {
      bf16x8 vf = ldg8(Vp + (size_t)(nt * 16 + lc) * L + kb * 32 + quad * 8);
      o[nt] = __builtin_amdgcn_mfma_f32_16x16x32_bf16(af, vf, o[nt], 0, 0, 0);
    }
  }
  const int b = bh >> 4, h = bh & 15;
#pragma unroll
  for (int r = 0; r < 4; ++r) {
    int qi = quad * 4 + r;
    float li = linv[wave][qi];
    size_t base = ((size_t)b * L + (qw + qi)) * 1024 + h * 64;
#pragma unroll
    for (int nt = 0; nt < 4; ++nt)
      Ao[base + nt * 16 + lc] = f2bf(o[nt][r] * li);
  }
}

// ------------------------------ launcher -----------------------------------
extern "C" void kernel_launch(void* const* d_in, const int* in_sizes, int n_in,
                              void* d_out, int out_size, void* d_ws, size_t ws_size,
                              hipStream_t stream) {
  const float* q   = (const float*)d_in[0];
  const float* k   = (const float*)d_in[1];
  const float* v   = (const float*)d_in[2];
  const float* w_q = (const float*)d_in[3];
  const float* b_q = (const float*)d_in[4];
  const float* w_k = (const float*)d_in[5];
  const float* b_k = (const float*)d_in[6];
  const float* w_v = (const float*)d_in[7];
  const float* b_v = (const float*)d_in[8];
  const float* w_o = (const float*)d_in[9];
  const float* b_o = (const float*)d_in[10];
  const float* E   = (const float*)d_in[11];
  uint16_t* ws = (uint16_t*)d_ws;

  cast_kernel<<<4096, 256, 0, stream>>>(q, k, v, w_q, w_k, w_v, w_o, E, ws);

  gemm_bt<0, 6144, 1024><<<dim3(8, 48), 256, 0, stream>>>(ws + OXQ, ws + OWQ, b_q, ws + OQH);
  gemm_bt<1, 6144, 1024><<<dim3(8, 48), 256, 0, stream>>>(ws + OXK, ws + OWK, b_k, ws + OKH);
  gemm_bt<2, 1024, 6144><<<dim3(48, 8), 256, 0, stream>>>(ws + OWV, ws + OXV, b_v, ws + OVT);

  attn_kernel<<<dim3(24, 128), 128, 0, stream>>>(ws + OQH, ws + OKH, ws + OVT, ws + OEB, ws + OAO);

  gemm_bt<3, 6144, 1024><<<dim3(8, 48), 256, 0, stream>>>(ws + OAO, ws + OWO, b_o, d_out);
}